// Round 9
// baseline (384.769 us; speedup 1.0000x reference)
//
#include <hip/hip_runtime.h>
#include <hip/hip_cooperative_groups.h>

namespace cg = cooperative_groups;

typedef unsigned long long u64;
typedef unsigned int u32;

#define NB 64      // graphs
#define NN 128     // nodes per graph
#define NITER 5
#define NGEN 6     // initial labels + 5 WL iterations
#define SALT 0xD1B54A32D192ED03ULL
#define TSLOTS 256
#define NBLKC 1008 // = 2016 pairs / 2 per block

__device__ __forceinline__ u64 mix64(u64 x) {
    u64 z = x + 0x9E3779B97F4A7C15ULL;
    z = (z ^ (z >> 30)) * 0xBF58476D1CE4E5B9ULL;
    z = (z ^ (z >> 27)) * 0x94D049BB133111EBULL;
    return z ^ (z >> 31);
}

union ShMem {
    struct { u64 bits[2][NN]; u64 gsh[2][NN]; } p1;            // 4 KiB  (WL)
    struct { u64 keys[TSLOTS]; u32 cnts[TSLOTS]; } tb;         // 3 KiB  (table build)
    struct { u64 keys[NGEN*TSLOTS]; u32 cnts[NGEN*TSLOTS]; } pr; // 18 KiB (pair probe)
};

// Single cooperative dispatch: WL chain -> grid.sync -> table build ->
// grid.sync -> pair probes. 1008 blocks x 256 threads, 4 blocks/CU
// co-resident (18KB LDS, <=128 VGPR).
__global__ __launch_bounds__(256, 4) void wl_coop(const float* __restrict__ adj,
                                                  const int* __restrict__ labels,
                                                  u64* __restrict__ hgen,
                                                  u64* __restrict__ keysg,
                                                  u32* __restrict__ cntsg,
                                                  u32* __restrict__ KdiagU,
                                                  float* __restrict__ out) {
    cg::grid_group grid = cg::this_grid();
    const int blk = blockIdx.x;
    const int t = threadIdx.x;

    __shared__ ShMem sh;
    __shared__ u32 red[4];

    // ================= phase 1a: WL chain (blocks 0..63) =================
    if (blk < NB) {
        const int b = blk;
        const int u = t & 127;
        const int half = t >> 7;

        // pack: thread (u,half) builds 64-bit half-mask of row u
        {
            const float* rowp = adj + ((size_t)b * NN + u) * NN + half * 64;
            u64 m = 0;
            #pragma unroll
            for (int k = 0; k < 16; ++k) {
                const float4 v = *(const float4*)(rowp + 4 * k);
                u64 b4 = (v.x > 0.5f ? 1ULL : 0) | (v.y > 0.5f ? 2ULL : 0)
                       | (v.z > 0.5f ? 4ULL : 0) | (v.w > 0.5f ? 8ULL : 0);
                m |= b4 << (4 * k);
            }
            sh.p1.bits[half][u] = m;
        }
        u64 h = 0;
        if (t < NN) {
            h = mix64((u64)(u32)labels[b * NN + t]);
            hgen[(size_t)b * (NGEN * NN) + t] = h;
        }
        if (t == 0) { out[b * NB + b] = 1.0f; KdiagU[b] = 0u; }
        __syncthreads();

        u64 mA = 0, mB = 0;
        if (t < NN) { mA = sh.p1.bits[0][u]; mB = sh.p1.bits[1][u]; }
        for (int it = 0; it < NITER; ++it) {
            if (t < NN) sh.p1.gsh[it & 1][u] = mix64(h ^ SALT);
            __syncthreads();   // ping-pong: one barrier per iteration is safe
            if (t < NN) {
                const u64* gp = sh.p1.gsh[it & 1];
                u64 s = 0;
                u64 mm = mA;
                while (mm) { int j = __builtin_ctzll(mm); mm &= mm - 1; s += gp[j]; }
                mm = mB;
                while (mm) { int j = __builtin_ctzll(mm); mm &= mm - 1; s += gp[64 + j]; }
                h = mix64(mix64(h) + s);
                hgen[(size_t)b * (NGEN * NN) + (it + 1) * NN + t] = h;
            }
        }
    }
    __threadfence();
    grid.sync();

    // ============ phase 1b: hash tables (blocks 0..383, one per (b,gen)) ============
    if (blk < NB * NGEN) {
        const int bg = blk;
        sh.tb.keys[t] = 0ULL;
        sh.tb.cnts[t] = 0u;
        __syncthreads();
        if (t < NN) {
            const u64 key = hgen[(size_t)bg * NN + t];
            u32 s = (u32)key & (TSLOTS - 1);
            for (;;) {
                u64 old = atomicCAS((unsigned long long*)&sh.tb.keys[s], 0ULL, key);
                if (old == 0ULL || old == key) { atomicAdd(&sh.tb.cnts[s], 1u); break; }
                s = (s + 1) & (TSLOTS - 1);
            }
        }
        __syncthreads();
        {
            const u64 kk = sh.tb.keys[t];
            const u32 cc = sh.tb.cnts[t];
            keysg[(size_t)bg * TSLOTS + t] = kk;
            cntsg[(size_t)bg * TSLOTS + t] = cc;
            u32 acc = cc * cc;
            #pragma unroll
            for (int off = 32; off > 0; off >>= 1) acc += __shfl_down(acc, off);
            if ((t & 63) == 0) atomicAdd(&KdiagU[bg / NGEN], acc);
        }
    }
    __threadfence();
    grid.sync();

    // ================= phase 2: pair probes (2 pairs per block) =================
    #pragma unroll 1
    for (int pp = 0; pp < 2; ++pp) {
        const int p = blk * 2 + pp;   // 0..2015
        int b1 = (int)((1.0f + sqrtf(1.0f + 8.0f * (float)p)) * 0.5f);
        while (b1 * (b1 - 1) / 2 > p) --b1;
        while ((b1 + 1) * b1 / 2 <= p) ++b1;
        const int b2 = p - b1 * (b1 - 1) / 2;

        __syncthreads();   // LDS reuse guard
        {   // stage b2's tables (SoA): keys 768 x ulonglong2, counts 384 x uint4
            const ulonglong2* srcK = (const ulonglong2*)(keysg + (size_t)b2 * NGEN * TSLOTS);
            ulonglong2* dstK = (ulonglong2*)sh.pr.keys;
            #pragma unroll
            for (int k = 0; k < 3; ++k) dstK[t + 256 * k] = srcK[t + 256 * k];
            const uint4* srcC = (const uint4*)(cntsg + (size_t)b2 * NGEN * TSLOTS);
            uint4* dstC = (uint4*)sh.pr.cnts;
            dstC[t] = srcC[t];
            if (t < 128) dstC[t + 256] = srcC[t + 256];
        }
        __syncthreads();

        u32 c = 0;
        const u64* abase = hgen + (size_t)b1 * NGEN * NN;
        #pragma unroll
        for (int k = 0; k < 3; ++k) {
            const int idx = t + 256 * k;        // 0..767 -> gen = idx>>7
            const u64 a = abase[idx];
            const int base = (idx >> 7) * TSLOTS;
            u32 s = (u32)a & (TSLOTS - 1);
            for (;;) {
                const u64 kk = sh.pr.keys[base + s];
                if (kk == a) { c += sh.pr.cnts[base + s]; break; }
                if (kk == 0ULL) break;
                s = (s + 1) & (TSLOTS - 1);
            }
        }
        #pragma unroll
        for (int off = 32; off > 0; off >>= 1) c += __shfl_down(c, off);
        if ((t & 63) == 0) red[t >> 6] = c;
        __syncthreads();
        if (t == 0) {
            const float v = (float)(red[0] + red[1] + red[2] + red[3])
                          / (sqrtf((float)KdiagU[b1]) * sqrtf((float)KdiagU[b2]));
            out[b1 * NB + b2] = v;
            out[b2 * NB + b1] = v;
        }
    }
}

extern "C" void kernel_launch(void* const* d_in, const int* in_sizes, int n_in,
                              void* d_out, int out_size, void* d_ws, size_t ws_size,
                              hipStream_t stream) {
    const float* adj   = (const float*)d_in[0];   // [64,128,128] fp32 (0/1)
    const int*  labels = (const int*)d_in[1];     // [64,128] int32
    float* out = (float*)d_out;                   // [64,64] fp32

    char* ws = (char*)d_ws;
    u64* hgen   = (u64*)ws;                        // 64*768*8  = 384 KiB
    u64* keysg  = (u64*)(ws + 512 * 1024);         // 64*1536*8 = 768 KiB
    u32* cntsg  = (u32*)(ws + 1536 * 1024);        // 64*1536*4 = 384 KiB
    u32* KdiagU = (u32*)(ws + 2048 * 1024);        // 256 B

    void* args[] = { (void*)&adj, (void*)&labels, (void*)&hgen,
                     (void*)&keysg, (void*)&cntsg, (void*)&KdiagU, (void*)&out };
    hipLaunchCooperativeKernel((const void*)wl_coop, dim3(NBLKC), dim3(256),
                               args, 0, stream);
}

// Round 10
// 279.230 us; speedup vs baseline: 1.3780x; 1.3780x over previous
//
#include <hip/hip_runtime.h>

typedef unsigned long long u64;
typedef unsigned int u32;

#define NB 64      // graphs
#define NN 128     // nodes per graph
#define NITER 5
#define NGEN 6     // initial labels + 5 WL iterations
#define SALT 0xD1B54A32D192ED03ULL
#define NPAIR_OFF (NB*(NB-1)/2)  // 2016 strict lower pairs
#define TSLOTS 256

__device__ __forceinline__ u64 mix64(u64 x) {
    u64 z = x + 0x9E3779B97F4A7C15ULL;
    z = (z ^ (z >> 30)) * 0xBF58476D1CE4E5B9ULL;
    z = (z ^ (z >> 27)) * 0x94D049BB133111EBULL;
    return z ^ (z >> 31);
}

union ShMem {
    struct {                      // producer (WL) phase: 10 KiB
        u64 bits[2][NN];          // half-row adjacency masks
        u64 gsh[2][NN];           // ping-pong neighbor feed
        u64 hall[NGEN][NN];       // all 6 generations
    } p;
    struct {                      // consumer (probe) phase: 18 KiB
        u64 keys[NGEN * TSLOTS];
        u32 cnts[NGEN * TSLOTS];
    } c;
};

// First-claimant-computes protocol. state[g]: 0 = free, 1 = claimed, 2 = done.
// Deadlock-free at any occupancy: a claimant is resident (it ran the CAS) and
// never waits while holding an unreleased claim.
__device__ __forceinline__ void ensure_graph(int g,
        const float* __restrict__ adj, const int* __restrict__ labels,
        u64* __restrict__ hgen, float* __restrict__ Kdiag,
        float* __restrict__ out, u32* __restrict__ state,
        ShMem* sh, u32* red, u32* flag_sh) {
    const int t = threadIdx.x;
    if (t == 0) *flag_sh = atomicCAS(&state[g], 0u, 1u);
    __syncthreads();
    const u32 st = *flag_sh;

    if (st == 0) {
        // ---------- we are the producer for graph g ----------
        const int u = t & 127;
        const int half = t >> 7;
        {   // pack: thread (u,half) builds a 64-bit half-row mask
            const float* rowp = adj + ((size_t)g * NN + u) * NN + half * 64;
            u64 m = 0;
            #pragma unroll
            for (int k = 0; k < 16; ++k) {
                const float4 v = *(const float4*)(rowp + 4 * k);
                u64 b4 = (v.x > 0.5f ? 1ULL : 0) | (v.y > 0.5f ? 2ULL : 0)
                       | (v.z > 0.5f ? 4ULL : 0) | (v.w > 0.5f ? 8ULL : 0);
                m |= b4 << (4 * k);
            }
            sh->p.bits[half][u] = m;
        }
        u64 h = 0;
        if (t < NN) {
            h = mix64((u64)(u32)labels[g * NN + t]);
            sh->p.hall[0][t] = h;
            hgen[(size_t)g * (NGEN * NN) + t] = h;
        }
        __syncthreads();
        u64 mA = 0, mB = 0;
        if (t < NN) { mA = sh->p.bits[0][t]; mB = sh->p.bits[1][t]; }
        for (int it = 0; it < NITER; ++it) {
            if (t < NN) sh->p.gsh[it & 1][t] = mix64(h ^ SALT);
            __syncthreads();           // ping-pong: 1 barrier/iter
            if (t < NN) {
                const u64* gp = sh->p.gsh[it & 1];
                u64 s = 0, mm = mA;
                while (mm) { int j = __builtin_ctzll(mm); mm &= mm - 1; s += gp[j]; }
                mm = mB;
                while (mm) { int j = __builtin_ctzll(mm); mm &= mm - 1; s += gp[64 + j]; }
                h = mix64(mix64(h) + s);
                sh->p.hall[it + 1][t] = h;
                hgen[(size_t)g * (NGEN * NN) + (it + 1) * NN + t] = h;
            }
        }
        __syncthreads();
        // diagonal: K[g,g] via broadcast-read compares (384/thread)
        u32 cnt = 0;
        const int jh = t >> 7;
        for (int gen = 0; gen < NGEN; ++gen) {
            const u64 a = sh->p.hall[gen][u];
            const u64* jp = &sh->p.hall[gen][jh * 64];  // wave-uniform base
            #pragma unroll
            for (int j = 0; j < 64; ++j) cnt += (a == jp[j]) ? 1u : 0u;
        }
        #pragma unroll
        for (int off = 32; off > 0; off >>= 1) cnt += __shfl_down(cnt, off);
        if ((t & 63) == 0) red[t >> 6] = cnt;
        __syncthreads();
        if (t == 0) {
            const u32 d = red[0] + red[1] + red[2] + red[3];
            Kdiag[g] = sqrtf((float)d);
            out[g * NB + g] = 1.0f;
            __threadfence();                       // release hgen/Kdiag/out
            atomicExch(&state[g], 2u);
        }
    } else {
        // ---------- already claimed/done: acquire-spin until released ----------
        if (t == 0) {
            while (__hip_atomic_load(&state[g], __ATOMIC_ACQUIRE,
                                     __HIP_MEMORY_SCOPE_AGENT) != 2u)
                __builtin_amdgcn_s_sleep(8);
        }
    }
    __syncthreads();   // flag_sh / LDS reuse guard for caller
}

// One ordinary dispatch: 2016 blocks x 256 threads, one block per strict
// lower pair (b1>b2). Ensures both graphs' WL chains exist (claim protocol),
// then builds b2's 6 hash tables in LDS from hgen and probes with b1's labels.
__global__ __launch_bounds__(256) void wl_fused2(const float* __restrict__ adj,
                                                 const int* __restrict__ labels,
                                                 u64* __restrict__ hgen,
                                                 float* __restrict__ Kdiag,
                                                 u32* __restrict__ state,
                                                 float* __restrict__ out) {
    const int p = blockIdx.x;
    int b1 = (int)((1.0f + sqrtf(1.0f + 8.0f * (float)p)) * 0.5f);
    while (b1 * (b1 - 1) / 2 > p) --b1;
    while ((b1 + 1) * b1 / 2 <= p) ++b1;
    const int b2 = p - b1 * (b1 - 1) / 2;

    const int t = threadIdx.x;
    __shared__ ShMem sh;
    __shared__ u32 red[4];
    __shared__ u32 flag_sh;

    ensure_graph(b1, adj, labels, hgen, Kdiag, out, state, &sh, red, &flag_sh);
    ensure_graph(b2, adj, labels, hgen, Kdiag, out, state, &sh, red, &flag_sh);

    // ---------- consumer: build b2's tables in LDS ----------
    #pragma unroll
    for (int k = 0; k < 6; ++k) sh.c.keys[t + 256 * k] = 0ULL;
    #pragma unroll
    for (int k = 0; k < 6; ++k) sh.c.cnts[t + 256 * k] = 0u;
    __syncthreads();

    const u64* lb2 = hgen + (size_t)b2 * (NGEN * NN);
    #pragma unroll
    for (int k = 0; k < 3; ++k) {
        const int idx = t + 256 * k;          // 0..767, gen = idx>>7
        const u64 key = lb2[idx];
        const u32 base = (u32)(idx >> 7) * TSLOTS;
        u32 s = (u32)key & (TSLOTS - 1);
        for (;;) {
            u64 old = atomicCAS((unsigned long long*)&sh.c.keys[base + s], 0ULL, key);
            if (old == 0ULL || old == key) { atomicAdd(&sh.c.cnts[base + s], 1u); break; }
            s = (s + 1) & (TSLOTS - 1);
        }
    }
    __syncthreads();

    // ---------- probe with b1's labels ----------
    u32 c = 0;
    const u64* lb1 = hgen + (size_t)b1 * (NGEN * NN);
    #pragma unroll
    for (int k = 0; k < 3; ++k) {
        const int idx = t + 256 * k;
        const u64 a = lb1[idx];
        const u32 base = (u32)(idx >> 7) * TSLOTS;
        u32 s = (u32)a & (TSLOTS - 1);
        for (;;) {
            const u64 kk = sh.c.keys[base + s];
            if (kk == a) { c += sh.c.cnts[base + s]; break; }
            if (kk == 0ULL) break;
            s = (s + 1) & (TSLOTS - 1);
        }
    }

    #pragma unroll
    for (int off = 32; off > 0; off >>= 1) c += __shfl_down(c, off);
    if ((t & 63) == 0) red[t >> 6] = c;
    __syncthreads();
    if (t == 0) {
        const float v = (float)(red[0] + red[1] + red[2] + red[3])
                      / (Kdiag[b1] * Kdiag[b2]);
        out[b1 * NB + b2] = v;
        out[b2 * NB + b1] = v;
    }
}

extern "C" void kernel_launch(void* const* d_in, const int* in_sizes, int n_in,
                              void* d_out, int out_size, void* d_ws, size_t ws_size,
                              hipStream_t stream) {
    const float* adj   = (const float*)d_in[0];   // [64,128,128] fp32 (0/1)
    const int*  labels = (const int*)d_in[1];     // [64,128] int32
    float* out = (float*)d_out;                   // [64,64] fp32

    char* ws = (char*)d_ws;
    u64*   hgen  = (u64*)ws;                       // 64*768*8 = 384 KiB
    float* Kdiag = (float*)(ws + 448 * 1024);      // 256 B
    u32*   state = (u32*)(ws + 452 * 1024);        // 256 B  (must start at 0)

    hipMemsetAsync(state, 0, NB * sizeof(u32), stream);
    wl_fused2<<<NPAIR_OFF, 256, 0, stream>>>(adj, labels, hgen, Kdiag, state, out);
}

// Round 11
// 37.612 us; speedup vs baseline: 10.2299x; 7.4239x over previous
//
#include <hip/hip_runtime.h>

typedef unsigned long long u64;
typedef unsigned int u32;

#define NB 64      // graphs
#define NN 128     // nodes per graph
#define NITER 5
#define NGEN 6     // initial labels + 5 WL iterations
#define SALT 0xD1B54A32D192ED03ULL
#define NPAIR_OFF (NB*(NB-1)/2)  // 2016 strict lower pairs
#define TSLOTS 256

__device__ __forceinline__ u64 mix64(u64 x) {
    u64 z = x + 0x9E3779B97F4A7C15ULL;
    z = (z ^ (z >> 30)) * 0xBF58476D1CE4E5B9ULL;
    z = (z ^ (z >> 27)) * 0x94D049BB133111EBULL;
    return z ^ (z >> 31);
}

// K1: per-graph WL chain + Kdiag. 64 blocks x 512 threads. Idempotent.
// - pack: wave w ballots rows w*16..+15 (coalesced 256B/instr loads)
// - WL: t<128, full 128-bit mask in 2 VGPRs, ping-pong gsh -> 1 barrier/iter
// - diag: broadcast-compare over hall (192 cmp/thread), no atomics
__global__ __launch_bounds__(512) void wl_iter(const float* __restrict__ adj,
                                               const int* __restrict__ labels,
                                               u64* __restrict__ hgen,
                                               float* __restrict__ Kdiag,
                                               float* __restrict__ out) {
    const int b = blockIdx.x;
    const int t = threadIdx.x;
    const int wave = t >> 6;   // 0..7
    const int lane = t & 63;

    __shared__ u64 bits_sh[NN][2];   // 2 KiB
    __shared__ u64 gsh[2][NN];       // 2 KiB ping-pong
    __shared__ u64 hall[NGEN][NN];   // 6 KiB
    __shared__ u32 part[8];

    // ---- coalesced ballot pack: wave w -> rows w*16 .. w*16+15 ----
    {
        const float* abase = adj + (size_t)b * NN * NN;
        #pragma unroll
        for (int k = 0; k < 16; ++k) {
            const int row = wave * 16 + k;
            const float* arow = abase + (size_t)row * NN;
            u64 m0 = __ballot(arow[lane] > 0.5f);
            u64 m1 = __ballot(arow[64 + lane] > 0.5f);
            if (lane == 0) { bits_sh[row][0] = m0; bits_sh[row][1] = m1; }
        }
    }

    u64 h = 0;
    if (t < NN) {
        h = mix64((u64)(u32)labels[b * NN + t]);
        hall[0][t] = h;
        hgen[(size_t)b * (NGEN * NN) + t] = h;
    }
    __syncthreads();

    u64 mA = 0, mB = 0;
    if (t < NN) { mA = bits_sh[t][0]; mB = bits_sh[t][1]; }

    for (int it = 0; it < NITER; ++it) {
        if (t < NN) gsh[it & 1][t] = mix64(h ^ SALT);
        __syncthreads();   // ping-pong: single barrier per iteration is safe
        if (t < NN) {
            const u64* gp = gsh[it & 1];
            u64 s = 0, mm = mA;
            while (mm) { int j = __builtin_ctzll(mm); mm &= mm - 1; s += gp[j]; }
            mm = mB;
            while (mm) { int j = __builtin_ctzll(mm); mm &= mm - 1; s += gp[64 + j]; }
            h = mix64(mix64(h) + s);
            hall[it + 1][t] = h;
            hgen[(size_t)b * (NGEN * NN) + (it + 1) * NN + t] = h;
        }
    }
    __syncthreads();

    // ---- diagonal: K[b,b] = #equal pairs over 6 gens ----
    {
        const int u = t & 127;
        const int jq = t >> 7;   // quarter 0..3
        u32 cnt = 0;
        for (int gen = 0; gen < NGEN; ++gen) {
            const u64 a = hall[gen][u];
            const u64* jp = &hall[gen][jq * 32];   // wave-uniform base -> broadcast
            #pragma unroll
            for (int j = 0; j < 32; ++j) cnt += (a == jp[j]) ? 1u : 0u;
        }
        #pragma unroll
        for (int off = 32; off > 0; off >>= 1) cnt += __shfl_down(cnt, off);
        if (lane == 0) part[wave] = cnt;
        __syncthreads();
        if (t == 0) {
            u32 d = 0;
            #pragma unroll
            for (int w = 0; w < 8; ++w) d += part[w];
            Kdiag[b] = sqrtf((float)d);
            out[b * NB + b] = 1.0f;
        }
    }
}

// K2: one block per strict lower pair (b1>b2), 256 threads. Idempotent.
// Builds b2's 6 hash tables in LDS directly from hgen (768 inserts), probes
// with b1's 768 labels (coalesced), writes both triangles normalized.
__global__ __launch_bounds__(256) void wl_pairs(const u64* __restrict__ hgen,
                                                const float* __restrict__ Kdiag,
                                                float* __restrict__ out) {
    const int p = blockIdx.x;
    int b1 = (int)((1.0f + sqrtf(1.0f + 8.0f * (float)p)) * 0.5f);
    while (b1 * (b1 - 1) / 2 > p) --b1;
    while ((b1 + 1) * b1 / 2 <= p) ++b1;
    const int b2 = p - b1 * (b1 - 1) / 2;

    const int t = threadIdx.x;
    __shared__ u64 keys[NGEN * TSLOTS];  // 12 KiB
    __shared__ u32 cnts[NGEN * TSLOTS];  // 6 KiB
    __shared__ u32 red[4];

    #pragma unroll
    for (int k = 0; k < 6; ++k) keys[t + 256 * k] = 0ULL;
    #pragma unroll
    for (int k = 0; k < 6; ++k) cnts[t + 256 * k] = 0u;
    __syncthreads();

    // ---- build b2's tables (3 inserts/thread, coalesced label reads) ----
    const u64* lb2 = hgen + (size_t)b2 * (NGEN * NN);
    #pragma unroll
    for (int k = 0; k < 3; ++k) {
        const int idx = t + 256 * k;          // 0..767, gen = idx>>7
        const u64 key = lb2[idx];
        const u32 base = (u32)(idx >> 7) * TSLOTS;
        u32 s = (u32)key & (TSLOTS - 1);
        for (;;) {
            u64 old = atomicCAS((unsigned long long*)&keys[base + s], 0ULL, key);
            if (old == 0ULL || old == key) { atomicAdd(&cnts[base + s], 1u); break; }
            s = (s + 1) & (TSLOTS - 1);
        }
    }
    __syncthreads();

    // ---- probe with b1's labels ----
    u32 c = 0;
    const u64* lb1 = hgen + (size_t)b1 * (NGEN * NN);
    #pragma unroll
    for (int k = 0; k < 3; ++k) {
        const int idx = t + 256 * k;
        const u64 a = lb1[idx];
        const u32 base = (u32)(idx >> 7) * TSLOTS;
        u32 s = (u32)a & (TSLOTS - 1);
        for (;;) {
            const u64 kk = keys[base + s];
            if (kk == a) { c += cnts[base + s]; break; }
            if (kk == 0ULL) break;
            s = (s + 1) & (TSLOTS - 1);
        }
    }

    #pragma unroll
    for (int off = 32; off > 0; off >>= 1) c += __shfl_down(c, off);
    if ((t & 63) == 0) red[t >> 6] = c;
    __syncthreads();
    if (t == 0) {
        const float v = (float)(red[0] + red[1] + red[2] + red[3])
                      / (Kdiag[b1] * Kdiag[b2]);
        out[b1 * NB + b2] = v;
        out[b2 * NB + b1] = v;
    }
}

extern "C" void kernel_launch(void* const* d_in, const int* in_sizes, int n_in,
                              void* d_out, int out_size, void* d_ws, size_t ws_size,
                              hipStream_t stream) {
    const float* adj   = (const float*)d_in[0];   // [64,128,128] fp32 (0/1)
    const int*  labels = (const int*)d_in[1];     // [64,128] int32
    float* out = (float*)d_out;                   // [64,64] fp32

    char* ws = (char*)d_ws;
    u64*   hgen  = (u64*)ws;                       // 64*768*8 = 384 KiB
    float* Kdiag = (float*)(ws + 448 * 1024);      // 256 B

    wl_iter <<<NB, 512, 0, stream>>>(adj, labels, hgen, Kdiag, out);
    wl_pairs<<<NPAIR_OFF, 256, 0, stream>>>(hgen, Kdiag, out);
}

// Round 12
// 30.496 us; speedup vs baseline: 12.6172x; 1.2334x over previous
//
#include <hip/hip_runtime.h>

typedef unsigned long long u64;
typedef unsigned int u32;

#define NB 64      // graphs
#define NN 128     // nodes per graph
#define NITER 5
#define NGEN 6     // initial labels + 5 WL iterations
#define SALT 0xD1B54A32D192ED03ULL
#define NPAIR_OFF (NB*(NB-1)/2)  // 2016 strict lower pairs
#define TSLOTS 256

__device__ __forceinline__ u64 mix64(u64 x) {
    u64 z = x + 0x9E3779B97F4A7C15ULL;
    z = (z ^ (z >> 30)) * 0xBF58476D1CE4E5B9ULL;
    z = (z ^ (z >> 27)) * 0x94D049BB133111EBULL;
    return z ^ (z >> 31);
}

// K1: per-graph WL chain + Kdiag. 64 blocks x 512 threads. Idempotent.
// - pack: coalesced ballot (wave w -> rows w*16..+15, 256B/instr)
// - WL: DENSE predicated quarter-walk: thread (u,q) sums 32 static-address
//   broadcast LDS reads under its 32-bit mask quarter -> no dependent-load
//   chain (vs serial ctz walk), psum combine, 2 barriers/iter
// - diag: broadcast-compare over all 6 generations, no atomics
__global__ __launch_bounds__(512) void wl_iter(const float* __restrict__ adj,
                                               const int* __restrict__ labels,
                                               u64* __restrict__ hgen,
                                               float* __restrict__ Kdiag,
                                               float* __restrict__ out) {
    const int b = blockIdx.x;
    const int t = threadIdx.x;
    const int wave = t >> 6;   // 0..7
    const int lane = t & 63;
    const int u = t & 127;     // node
    const int q = t >> 7;      // quarter 0..3

    __shared__ u64 bits_sh[NN][2];   // 2 KiB row masks
    __shared__ u64 gsh[NN];          // 1 KiB neighbor feed
    __shared__ u64 psum[3][NN];      // 3 KiB quarter partials (q=1..3)
    __shared__ u64 hall[NGEN][NN];   // 6 KiB all generations
    __shared__ u32 part[8];

    // ---- coalesced ballot pack: wave w -> rows w*16 .. w*16+15 ----
    {
        const float* abase = adj + (size_t)b * NN * NN;
        #pragma unroll
        for (int k = 0; k < 16; ++k) {
            const int row = wave * 16 + k;
            const float* arow = abase + (size_t)row * NN;
            u64 m0 = __ballot(arow[lane] > 0.5f);
            u64 m1 = __ballot(arow[64 + lane] > 0.5f);
            if (lane == 0) { bits_sh[row][0] = m0; bits_sh[row][1] = m1; }
        }
    }

    u64 h = 0;
    if (t < NN) {
        h = mix64((u64)(u32)labels[b * NN + t]);
        hall[0][t] = h;
        hgen[(size_t)b * (NGEN * NN) + t] = h;
    }
    __syncthreads();

    // 32-bit quarter mask of row u, cols q*32 .. q*32+31
    const u32 qm = (u32)(bits_sh[u][q >> 1] >> ((q & 1) * 32));

    for (int it = 0; it < NITER; ++it) {
        if (t < NN) gsh[t] = mix64(h ^ SALT);
        __syncthreads();
        // dense predicated walk: 32 broadcast reads, fully pipelined
        u64 s = 0;
        {
            const u64* gp = gsh + q * 32;
            #pragma unroll
            for (int j = 0; j < 32; ++j) {
                const u64 g = gp[j];
                s += ((qm >> j) & 1u) ? g : 0ULL;
            }
        }
        if (q) psum[q - 1][u] = s;
        __syncthreads();
        if (t < NN) {
            h = mix64(mix64(h) + s + psum[0][u] + psum[1][u] + psum[2][u]);
            hall[it + 1][t] = h;
            hgen[(size_t)b * (NGEN * NN) + (it + 1) * NN + t] = h;
        }
    }
    __syncthreads();

    // ---- diagonal: K[b,b] = #equal ordered pairs over 6 gens ----
    {
        u32 cnt = 0;
        for (int gen = 0; gen < NGEN; ++gen) {
            const u64 a = hall[gen][u];
            const u64* jp = &hall[gen][q * 32];   // wave-uniform base -> broadcast
            #pragma unroll
            for (int j = 0; j < 32; ++j) cnt += (a == jp[j]) ? 1u : 0u;
        }
        #pragma unroll
        for (int off = 32; off > 0; off >>= 1) cnt += __shfl_down(cnt, off);
        if (lane == 0) part[wave] = cnt;
        __syncthreads();
        if (t == 0) {
            u32 d = 0;
            #pragma unroll
            for (int w = 0; w < 8; ++w) d += part[w];
            Kdiag[b] = sqrtf((float)d);
            out[b * NB + b] = 1.0f;
        }
    }
}

// K2: per-(graph,generation) hash table build — 384 independent blocks.
// 256-slot open addressing; exports SoA keys/counts. Idempotent in effect
// (table layout may vary with insert race order; probe results do not).
__global__ __launch_bounds__(128) void wl_tables(const u64* __restrict__ hgen,
                                                 u64* __restrict__ keysg,
                                                 u32* __restrict__ cntsg) {
    const int bg = blockIdx.x;   // b*NGEN + gen
    const int t = threadIdx.x;

    __shared__ u64 keys[TSLOTS];
    __shared__ u32 cnts[TSLOTS];
    keys[t] = 0ULL; keys[t + 128] = 0ULL;
    cnts[t] = 0u;   cnts[t + 128] = 0u;
    __syncthreads();

    const u64 h = hgen[(size_t)bg * NN + t];
    u32 s = (u32)h & (TSLOTS - 1);
    for (;;) {
        u64 old = atomicCAS((unsigned long long*)&keys[s], 0ULL, h);
        if (old == 0ULL || old == h) { atomicAdd(&cnts[s], 1u); break; }
        s = (s + 1) & (TSLOTS - 1);
    }
    __syncthreads();

    keysg[(size_t)bg * TSLOTS + t]       = keys[t];
    keysg[(size_t)bg * TSLOTS + t + 128] = keys[t + 128];
    cntsg[(size_t)bg * TSLOTS + t]       = cnts[t];
    cntsg[(size_t)bg * TSLOTS + t + 128] = cnts[t + 128];
}

// K3: one block per strict lower pair (b1>b2), 256 threads. Idempotent.
// Stage b2's 6 tables (SoA, 18 KiB -> 8 blocks/CU), probe with b1's 768
// labels (3/thread, coalesced), normalize, write both triangles.
__global__ __launch_bounds__(256) void wl_pairs(const u64* __restrict__ hgen,
                                                const u64* __restrict__ keysg,
                                                const u32* __restrict__ cntsg,
                                                const float* __restrict__ Kdiag,
                                                float* __restrict__ out) {
    const int p = blockIdx.x;
    int b1 = (int)((1.0f + sqrtf(1.0f + 8.0f * (float)p)) * 0.5f);
    while (b1 * (b1 - 1) / 2 > p) --b1;
    while ((b1 + 1) * b1 / 2 <= p) ++b1;
    const int b2 = p - b1 * (b1 - 1) / 2;

    const int t = threadIdx.x;
    __shared__ u64 keys[NGEN * TSLOTS];  // 12 KiB
    __shared__ u32 cnts[NGEN * TSLOTS];  // 6 KiB
    __shared__ u32 red[4];

    {   // keys: 768 x ulonglong2 over 256 threads
        const ulonglong2* src = (const ulonglong2*)(keysg + (size_t)b2 * NGEN * TSLOTS);
        ulonglong2* dst = (ulonglong2*)keys;
        #pragma unroll
        for (int k = 0; k < 3; ++k) dst[t + 256 * k] = src[t + 256 * k];
    }
    {   // counts: 384 x uint4 over 256 threads
        const uint4* src = (const uint4*)(cntsg + (size_t)b2 * NGEN * TSLOTS);
        uint4* dst = (uint4*)cnts;
        #pragma unroll
        for (int k = 0; k < 2; ++k) {
            const int idx = t + 256 * k;
            if (idx < 384) dst[idx] = src[idx];
        }
    }
    __syncthreads();

    u32 c = 0;
    const u64* abase = hgen + (size_t)b1 * NGEN * NN;
    #pragma unroll
    for (int k = 0; k < 3; ++k) {
        const int idx = t + 256 * k;        // 0..767 -> gen = idx>>7
        const u64 a = abase[idx];
        const int base = (idx >> 7) * TSLOTS;
        u32 s = (u32)a & (TSLOTS - 1);
        for (;;) {
            const u64 kk = keys[base + s];
            if (kk == a) { c += cnts[base + s]; break; }
            if (kk == 0ULL) break;
            s = (s + 1) & (TSLOTS - 1);
        }
    }

    #pragma unroll
    for (int off = 32; off > 0; off >>= 1) c += __shfl_down(c, off);
    if ((t & 63) == 0) red[t >> 6] = c;
    __syncthreads();
    if (t == 0) {
        const float v = (float)(red[0] + red[1] + red[2] + red[3])
                      / (Kdiag[b1] * Kdiag[b2]);
        out[b1 * NB + b2] = v;
        out[b2 * NB + b1] = v;
    }
}

extern "C" void kernel_launch(void* const* d_in, const int* in_sizes, int n_in,
                              void* d_out, int out_size, void* d_ws, size_t ws_size,
                              hipStream_t stream) {
    const float* adj   = (const float*)d_in[0];   // [64,128,128] fp32 (0/1)
    const int*  labels = (const int*)d_in[1];     // [64,128] int32
    float* out = (float*)d_out;                   // [64,64] fp32

    char* ws = (char*)d_ws;
    u64*   hgen  = (u64*)ws;                       // 64*768*8  = 384 KiB
    float* Kdiag = (float*)(ws + 448 * 1024);      // 256 B
    u64*   keysg = (u64*)(ws + 512 * 1024);        // 384*256*8 = 768 KiB
    u32*   cntsg = (u32*)(ws + 1536 * 1024);       // 384*256*4 = 384 KiB

    wl_iter  <<<NB, 512, 0, stream>>>(adj, labels, hgen, Kdiag, out);
    wl_tables<<<NB * NGEN, 128, 0, stream>>>(hgen, keysg, cntsg);
    wl_pairs <<<NPAIR_OFF, 256, 0, stream>>>(hgen, keysg, cntsg, Kdiag, out);
}